// Round 5
// baseline (2114.648 us; speedup 1.0000x reference)
//
#include <hip/hip_runtime.h>

typedef _Float16 h4 __attribute__((ext_vector_type(4)));
typedef float f4 __attribute__((ext_vector_type(4)));

#define SEQ_LEN 50
#define HID 64
#define FSTRIDE 68   // final-h LDS row pitch in halves (pad vs 64)

#if __has_builtin(__builtin_amdgcn_exp2f)
#define EXP2(x) __builtin_amdgcn_exp2f(x)
#else
extern "C" __device__ float __ocml_native_exp2_f32(float);
#define EXP2(x) __ocml_native_exp2_f32(x)
#endif
#define RCP(x) __builtin_amdgcn_rcpf(x)

// v_mfma_f32_16x16x16_f16 is a CDNA1-era op still present on gfx950
// (cdna4_isa.md §10); its builtin compiled AND passed on this harness in
// R1/R3 (HAVE_MFMA16 path taken), so it is used unconditionally here.
#define MFMA16(A,B,C) __builtin_amdgcn_mfma_f32_16x16x16f16(A, B, C, 0, 0, 0)

#define LOG2E  1.442695041f
#define LOG2E2 2.885390082f

// R11 == R10 resubmitted verbatim (R4 bench was an infra failure: container
// acquisition died twice; the kernel was never compiled/run/measured).
//
// R10: barrier-free register-resident LSTM.
// Evidence: R1 (-14% trans issue) and R3 (2x per-wave ILP) both left duration
// pinned at ~1950us rocprof with no pipe >74% busy -> the limiter is the
// per-timestep barrier-coupled LDS round-trip (ds_write h -> barrier ->
// ds_read h) that lockstep-stalls all waves 50 times per sequence.
//
// Fix: ONE wave owns 16 sequences end-to-end, computing all 64 units.
// mfma_f32_16x16x16_f16 has D-layout == B-layout (col=lane&15,
// row/k = 4*(lane>>4)+idx). Tiles: [gi=gate 0..3][dq=unit-quarter 0..3],
// K chunked in 4x16. A lane's activated h4 for unit-group dq IS the
// B-fragment for k-chunk dq of the next step after f32->f16 cvt:
//   D row m=4q+r -> unit u=16dq+4q+r;  B k=4q+j in chunk kc -> u=16kc+4q+j.
// So h stays in registers; NO LDS h traffic, NO __syncthreads in the t-loop;
// waves fully independent.
// x-projection + bias via ext-MFMA (A nonzero only quad0 k=0,1; B={x,1,..}) —
// exact scheme hardware-verified in R1.
//
// Activation math (R6/R7, verified): pre-acts pre-scaled (i,f,o: log2e;
// g: 2log2e, folded into A). Cell kept in 2log2e domain. Paired rcp at both
// sites (R=rcp(Da*Db); 1/Da=R*Db). c' clamp 40 keeps paired products finite
// (tanh(40/2L2)=1-2e-12 == fp32 1.0, no output change).
//
// VGPR budget ~180 (Aw 64 + Ax 16 + h/c/acc/temps) -> (256,2): 2 waves/SIMD.
__global__ __launch_bounds__(256, 2)
void lstm_fused(const float* __restrict__ x,
                const float* __restrict__ W_ih,
                const float* __restrict__ W_hh,
                const float* __restrict__ b_ih,
                const float* __restrict__ b_hh,
                const float* __restrict__ W_fc,
                const float* __restrict__ b_fc,
                float* __restrict__ out)
{
    __shared__ float    sXT[SEQ_LEN * 64];   // x transposed: [t][seq-in-block]
    __shared__ _Float16 sF[64 * FSTRIDE];    // final h: [seq-in-block][unit]

    const int tid  = threadIdx.x;
    const int wave = tid >> 6;
    const int lane = tid & 63;
    const int col  = lane & 15;
    const int quad = lane >> 4;
    const int seqBase = blockIdx.x << 6;     // 64 sequences per block

    // ---- stage x transposed (coalesced: consecutive tid -> consecutive t)
    for (int i = tid; i < SEQ_LEN * 64; i += 256) {
        const int s = i / SEQ_LEN;
        const int t = i - s * SEQ_LEN;
        sXT[t * 64 + s] = x[(size_t)(seqBase + s) * SEQ_LEN + t];
    }

    // ---- resident weight fragments, pre-scaled (i,f,o: log2e; g: 2log2e)
    // A[m=col][k = kc*16 + quad*4 + j] for W_ext row n = gi*64 + dq*16 + col.
    h4 Aw[4][4][4];   // [gi][dq][kc]
    h4 Ax[4][4];      // [gi][dq]: {w_ih*s, bsum*s, 0, 0} on quad0, else 0
    #pragma unroll
    for (int gi = 0; gi < 4; ++gi) {
        const float scale = (gi == 2) ? LOG2E2 : LOG2E;
        #pragma unroll
        for (int dq = 0; dq < 4; ++dq) {
            const int n = gi * 64 + dq * 16 + col;
            h4 axf = {};
            if (quad == 0) {
                axf[0] = (_Float16)(W_ih[n] * scale);
                axf[1] = (_Float16)((b_ih[n] + b_hh[n]) * scale);
            }
            Ax[gi][dq] = axf;
            #pragma unroll
            for (int kc = 0; kc < 4; ++kc) {
                const float* wp = W_hh + (size_t)n * HID + kc * 16 + quad * 4;
                f4 w = *(const f4*)wp;
                h4 a;
                a[0] = (_Float16)(w[0] * scale);
                a[1] = (_Float16)(w[1] * scale);
                a[2] = (_Float16)(w[2] * scale);
                a[3] = (_Float16)(w[3] * scale);
                Aw[gi][dq][kc] = a;
            }
        }
    }

    const f4 z4 = {0.0f, 0.0f, 0.0f, 0.0f};

    // h (packed f16 B-fragments, h0=0) and cell state (2log2e domain)
    h4 hB[4] = {};
    float c[4][4];
    #pragma unroll
    for (int dq = 0; dq < 4; ++dq)
        #pragma unroll
        for (int r = 0; r < 4; ++r) c[dq][r] = 0.0f;

    __syncthreads();   // sXT ready; the ONLY barrier before the epilogue

    for (int t = 0; t < SEQ_LEN; ++t) {
        const float xt = sXT[t * 64 + wave * 16 + col];
        h4 bext = {};
        bext[0] = (_Float16)xt;
        bext[1] = (_Float16)1.0f;

        h4 hN[4];
        #pragma unroll
        for (int dq = 0; dq < 4; ++dq) {
            f4 acc[4];
            #pragma unroll
            for (int gi = 0; gi < 4; ++gi) {
                f4 a = MFMA16(Ax[gi][dq], bext, z4);
                #pragma unroll
                for (int kc = 0; kc < 4; ++kc)
                    a = MFMA16(Aw[gi][dq][kc], hB[kc], a);
                acc[gi] = a;
            }
            // paired-rcp activations (R1 verbatim): 5 exp2 + 1 rcp per unit
            h4 hv;
            #pragma unroll
            for (int rp = 0; rp < 2; ++rp) {
                const int r0 = rp * 2, r1 = r0 + 1;
                float EiA = EXP2(-acc[0][r0]);
                float EfA = EXP2(-acc[1][r0]);
                float EgA = EXP2( acc[2][r0]);
                float EoA = EXP2(-acc[3][r0]);
                float EiB = EXP2(-acc[0][r1]);
                float EfB = EXP2(-acc[1][r1]);
                float EgB = EXP2( acc[2][r1]);
                float EoB = EXP2(-acc[3][r1]);
                float piA = 1.0f + EiA, pfA = 1.0f + EfA;
                float pgA = 1.0f + EgA, poA = 1.0f + EoA;
                float piB = 1.0f + EiB, pfB = 1.0f + EfB;
                float pgB = 1.0f + EgB, poB = 1.0f + EoB;
                float t1A = piA * pgA,  t1B = piB * pgB;
                float DA  = pfA * t1A,  DB  = pfB * t1B;
                float vA  = fmaf(EgA, pfA, -pfA) * LOG2E2;
                float vB  = fmaf(EgB, pfB, -pfB) * LOG2E2;
                float numA = fmaf(c[dq][r0], t1A, vA);
                float numB = fmaf(c[dq][r1], t1B, vB);
                float R   = RCP(DA * DB);
                float cnA = fminf(numA * (R * DB), 40.0f);
                float cnB = fminf(numB * (R * DA), 40.0f);
                c[dq][r0] = cnA;
                c[dq][r1] = cnB;
                float EcA = EXP2(cnA), EcB = EXP2(cnB);
                float DhA = fmaf(poA, EcA, poA);
                float DhB = fmaf(poB, EcB, poB);
                float R2  = RCP(DhA * DhB);
                float rhA = R2 * DhB,  rhB = R2 * DhA;
                hv[r0] = (_Float16)fmaf(EcA, rhA, -rhA);
                hv[r1] = (_Float16)fmaf(EcB, rhB, -rhB);
            }
            hN[dq] = hv;
        }
        #pragma unroll
        for (int dq = 0; dq < 4; ++dq) hB[dq] = hN[dq];
    }

    // ---- epilogue: dump final h to LDS once, then FC reduce.
    // Lane (col,quad) holds units u = 16*dq + 4*quad + r for seq=col.
    #pragma unroll
    for (int dq = 0; dq < 4; ++dq)
        *(h4*)(sF + (wave * 16 + col) * FSTRIDE + dq * 16 + quad * 4) = hB[dq];
    __syncthreads();

    if (lane < 48) {
        const int sl = lane / 3;   // sequence within this wave's 16
        const int nc = lane % 3;   // class
        const _Float16* hp = sF + (wave * 16 + sl) * FSTRIDE;
        float a = b_fc[nc];
        #pragma unroll
        for (int u = 0; u < HID; ++u)
            a = fmaf((float)hp[u], W_fc[nc * HID + u], a);
        out[(size_t)(seqBase + wave * 16 + sl) * 3 + nc] = a;
    }
}

extern "C" void kernel_launch(void* const* d_in, const int* in_sizes, int n_in,
                              void* d_out, int out_size, void* d_ws, size_t ws_size,
                              hipStream_t stream) {
    const float* x    = (const float*)d_in[0];
    const float* W_ih = (const float*)d_in[1];
    const float* W_hh = (const float*)d_in[2];
    const float* b_ih = (const float*)d_in[3];
    const float* b_hh = (const float*)d_in[4];
    const float* W_fc = (const float*)d_in[5];
    const float* b_fc = (const float*)d_in[6];
    float* out = (float*)d_out;

    const int nSeq   = in_sizes[0] / SEQ_LEN;  // 512000
    const int blocks = nSeq / 64;              // 8000

    hipLaunchKernelGGL(lstm_fused, dim3(blocks), dim3(256), 0, stream,
                       x, W_ih, W_hh, b_ih, b_hh, W_fc, b_fc, out);
}